// Round 10
// baseline (43.354 us; speedup 1.0000x reference)
//
#include <hip/hip_runtime.h>
#include <hip/hip_bf16.h>

typedef float f32x4 __attribute__((ext_vector_type(4)));
typedef int   i32x4 __attribute__((ext_vector_type(4)));
typedef int   i32x8 __attribute__((ext_vector_type(8)));

#define NC 4096
#define ND 1024
#define NVP 256     // padded compact-row count (B*A = 256 annotations max)
#define EPSF 1e-10f
#define SCALE1 127  // E8M0 exponent byte for 2^0

// Fragment-tiled fp8 layout for compact F (round-8/9 verified):
//   frag id = kt*16 + R16, frag = 2048 B; byte = half*1024 + lane*16 + b
//   lane = hi*16+lo -> row = R16*16+lo, k = kt*128 + hi*32 + half*16 + b.

// ---------------- K1: mask+compact (redundant per block) + gather-convert F ----------------
__global__ __launch_bounds__(256)
void prep_kernel(const int* __restrict__ ann, int n_ann,
                 const float* __restrict__ F,
                 unsigned char* __restrict__ Fc, float* __restrict__ f2c,
                 int* __restrict__ vidx, int* __restrict__ nv,
                 float* __restrict__ accum) {
  __shared__ unsigned char mark[NC];
  __shared__ int wsum[4];
  __shared__ int vloc[NVP];
  __shared__ float rs[4];
  const int tid = threadIdx.x;
  const int lane = tid & 63, wid = tid >> 6;

  // deterministic mask + compaction, identical in every block (no global dep)
  for (int i = tid; i < NC; i += 256) mark[i] = 0;
  __syncthreads();
  for (int t = tid; t < n_ann; t += 256) {
    int idx = ann[t * 5 + 4];
    if (idx >= 0 && idx < NC) mark[idx] = 1;  // benign race: all write 1
  }
  __syncthreads();
  int base = tid * 16, lc = 0;
  #pragma unroll
  for (int k = 0; k < 16; ++k) lc += mark[base + k];
  int inc = lc;
  #pragma unroll
  for (int off = 1; off < 64; off <<= 1) {
    int v = __shfl_up(inc, off);
    if (lane >= off) inc += v;
  }
  if (lane == 63) wsum[wid] = inc;
  __syncthreads();
  int wbase = 0;
  for (int w = 0; w < wid; ++w) wbase += wsum[w];
  int pos = wbase + inc - lc;  // exclusive prefix
  for (int k = 0; k < 16; ++k)
    if (mark[base + k]) vloc[pos++] = base + k;
  const int total = wsum[0] + wsum[1] + wsum[2] + wsum[3];
  __syncthreads();
  for (int i = total + tid; i < NVP; i += 256) vloc[i] = 0;  // padded slots
  __syncthreads();

  if (blockIdx.x == 0) {
    for (int i = tid; i < NVP; i += 256) vidx[i] = vloc[i];
    if (tid == 0) *nv = total;
    if (tid < 8) accum[tid] = 0.f;  // re-zero every call (graph replay)
  }

  // gather-convert 16 compact slots; prefetch all rows to hide latency
  float4 vv[16];
  #pragma unroll
  for (int j = 0; j < 16; ++j) {
    int slot = blockIdx.x * 16 + j;
    float4 v = {0.f, 0.f, 0.f, 0.f};
    if (slot < total)
      v = *reinterpret_cast<const float4*>(F + (size_t)vloc[slot] * ND + tid * 4);
    vv[j] = v;
  }
  #pragma unroll 1
  for (int j = 0; j < 16; ++j) {
    int slot = blockIdx.x * 16 + j;
    float4 v = vv[j];
    int pk = __builtin_amdgcn_cvt_pk_fp8_f32(v.x, v.y, 0, false);   // bytes 0,1
    pk = __builtin_amdgcn_cvt_pk_fp8_f32(v.z, v.w, pk, true);       // bytes 2,3
    int d0 = tid * 4;
    int kt = d0 >> 7, hif = (d0 >> 5) & 3, half = (d0 >> 4) & 1, b = d0 & 15;
    int R16 = slot >> 4, lof = slot & 15;
    size_t fa = ((((size_t)kt * 16 + R16) * 2 + half) * 64 + hif * 16 + lof) * 16 + b;
    *reinterpret_cast<int*>(Fc + fa) = pk;
    float sq = v.x * v.x + v.y * v.y + v.z * v.z + v.w * v.w;
    #pragma unroll
    for (int off = 32; off; off >>= 1) sq += __shfl_down(sq, off);
    if (lane == 0) rs[wid] = sq;
    __syncthreads();
    if (tid == 0) f2c[slot] = rs[0] + rs[1] + rs[2] + rs[3];
    __syncthreads();
  }
}

// ---------------- K2: fused P-convert + masked 256x4096 GEMM + loss ----------------
#define LDFRAG(V, BASEPTR, FID)                                               \
  do {                                                                        \
    const unsigned char* _p = (BASEPTR) + (size_t)(FID) * 2048 + lane * 16;   \
    i32x4 _l0 = *(const i32x4*)(_p);                                          \
    i32x4 _l1 = *(const i32x4*)(_p + 1024);                                   \
    V = __builtin_shufflevector(_l0, _l1, 0, 1, 2, 3, 4, 5, 6, 7);            \
  } while (0)

__global__ __launch_bounds__(512)
void pgemm_kernel(const float* __restrict__ P,
                  const unsigned char* __restrict__ Fc,
                  const float* __restrict__ f2c,
                  const int* __restrict__ vidx, const int* __restrict__ nv,
                  float* __restrict__ psum, float* __restrict__ accum) {
  // [kt][16 rows][128 B], XOR-swizzled: byte_in_row ^= (row&7)<<4
  __shared__ __attribute__((aligned(16))) unsigned char bfrag[8 * 2048];
  __shared__ float p2l[16], psl[16], redI[8], redE[8];
  const int tid = threadIdx.x;
  const int lane = tid & 63, wid = tid >> 6;
  const int bj = blockIdx.x;  // 16 P rows per block

  // Phase A: single-pass P read (coalesced), norms + fp8 swizzled LDS frags
  {
    const int r = tid >> 5;    // row 0..15
    const int seg = tid & 31;  // float4 lane within row
    const float* src = P + (size_t)(bj * 16 + r) * ND;
    float sq = 0.f, sm = 0.f;
    #pragma unroll
    for (int i = 0; i < 8; ++i) {
      float4 v = *reinterpret_cast<const float4*>(src + (seg + i * 32) * 4);
      int pk = __builtin_amdgcn_cvt_pk_fp8_f32(v.x, v.y, 0, false);
      pk = __builtin_amdgcn_cvt_pk_fp8_f32(v.z, v.w, pk, true);
      // k = (seg + i*32)*4 -> kt = i, byte-in-row = seg*4
      int addr = i * 2048 + r * 128 + ((seg * 4) ^ ((r & 7) << 4));
      *reinterpret_cast<int*>(&bfrag[addr]) = pk;
      sq += v.x * v.x + v.y * v.y + v.z * v.z + v.w * v.w;
      sm += v.x + v.y + v.z + v.w;
    }
    #pragma unroll
    for (int off = 16; off; off >>= 1) {
      sq += __shfl_down(sq, off, 32);
      sm += __shfl_down(sm, off, 32);
    }
    if ((tid & 31) == 0) {
      p2l[r] = sq; psl[r] = sm;
      psum[bj * 16 + r] = sm;   // finalize needs mask_j per row
    }
  }
  __syncthreads();

  // Phase B: 8 waves, wave w owns compact-F rows [w*32, w*32+32)
  const int lo = lane & 15, hi = lane >> 4;
  f32x4 acc0 = {0.f, 0.f, 0.f, 0.f}, acc1 = acc0;
  const int fbase = wid * 2;
  #pragma unroll 4
  for (int kt = 0; kt < 8; ++kt) {
    i32x8 a0, a1, b;
    LDFRAG(a0, Fc, kt * 16 + fbase);
    LDFRAG(a1, Fc, kt * 16 + fbase + 1);
    {
      int x = (lo & 7) << 4;
      const unsigned char* bb = &bfrag[kt * 2048 + lo * 128];
      i32x4 l0 = *reinterpret_cast<const i32x4*>(bb + ((hi * 32) ^ x));
      i32x4 l1 = *reinterpret_cast<const i32x4*>(bb + ((hi * 32 + 16) ^ x));
      b = __builtin_shufflevector(l0, l1, 0, 1, 2, 3, 4, 5, 6, 7);
    }
    acc0 = __builtin_amdgcn_mfma_scale_f32_16x16x128_f8f6f4(
        a0, b, acc0, 0, 0, 0, SCALE1, 0, SCALE1);
    acc1 = __builtin_amdgcn_mfma_scale_f32_16x16x128_f8f6f4(
        a1, b, acc1, 0, 0, 0, SCALE1, 0, SCALE1);
  }

  // Epilogue. C/D layout: col = lane&15 (P row), row = (lane>>4)*4 + reg (F row).
  int Nv = *nv;
  float intra_l = 0.f, inter_l = 0.f;
  const int gj = bj * 16 + lo;
  const float p2j = p2l[lo];
  const bool mj = psl[lo] != 0.f;
  if (mj) {
    #pragma unroll
    for (int f = 0; f < 2; ++f) {
      f32x4 a = f ? acc1 : acc0;
      #pragma unroll
      for (int r = 0; r < 4; ++r) {
        int ci = wid * 32 + f * 16 + hi * 4 + r;
        if (ci < Nv) {
          float msd = fmaxf(f2c[ci] + p2j - 2.f * a[r], 0.f) * (1.f / 1024.f);
          int gi = vidx[ci];
          if (gi == gj) {
            intra_l += msd;                 // diagonal: intra
          } else if (msd < 1.0f) {          // inter term nonzero only if sqrt(msd)<1
            float s = sqrtf(fmaxf(msd, 1e-12f));
            float e = 1.f - s;
            float e2 = e * e;
            inter_l += e2 * e2;             // (e/M)^2 * max(e,0)^2, M=1
          }
        }
      }
    }
  }
  #pragma unroll
  for (int off = 32; off; off >>= 1) {
    intra_l += __shfl_down(intra_l, off);
    inter_l += __shfl_down(inter_l, off);
  }
  if (lane == 0) { redI[wid] = intra_l; redE[wid] = inter_l; }
  __syncthreads();
  if (tid == 0) {
    float si = 0.f, se = 0.f;
    #pragma unroll
    for (int w = 0; w < 8; ++w) { si += redI[w]; se += redE[w]; }
    atomicAdd(&accum[0], si);
    atomicAdd(&accum[1], se);
  }
}

// ---------------- K3: finalize (ni = Nv; nj, nd from psum/vidx) ----------------
__global__ void finalize_kernel(const float* __restrict__ psum,
                                const int* __restrict__ vidx,
                                const int* __restrict__ nv,
                                const float* __restrict__ accum,
                                float* __restrict__ out) {
  __shared__ int r1[4], r2[4];
  int tid = threadIdx.x;
  int Nv = *nv;
  int nj = 0, nd = 0;
  for (int i = tid; i < NC; i += 256) nj += (psum[i] != 0.f);
  for (int c = tid; c < Nv; c += 256) nd += (psum[vidx[c]] != 0.f);
  #pragma unroll
  for (int off = 32; off; off >>= 1) {
    nj += __shfl_down(nj, off);
    nd += __shfl_down(nd, off);
  }
  int wid = tid >> 6, lane = tid & 63;
  if (lane == 0) { r1[wid] = nj; r2[wid] = nd; }
  __syncthreads();
  if (tid == 0) {
    float fni = (float)Nv;
    float fnj = (float)(r1[0] + r1[1] + r1[2] + r1[3]);
    float fnd = (float)(r2[0] + r2[1] + r2[2] + r2[3]);
    out[0] = accum[0] / (fnd + EPSF);
    out[1] = accum[1] / (fni * fnj - fnd + EPSF);
  }
}

extern "C" void kernel_launch(void* const* d_in, const int* in_sizes, int n_in,
                              void* d_out, int out_size, void* d_ws, size_t ws_size,
                              hipStream_t stream) {
  const float* F = (const float*)d_in[0];
  const float* P = (const float*)d_in[1];
  const int* ann = (const int*)d_in[2];
  int n_ann = in_sizes[2] / 5;

  char* ws = (char*)d_ws;
  unsigned char* Fc = (unsigned char*)ws;              // 256 KB frag-tiled fp8
  float* f2c   = (float*)(ws + (size_t)NVP * ND);      // 256 f32
  float* psum  = f2c + NVP;                            // 4096 f32
  float* accum = psum + NC;                            // 8 f32
  int*   vidx  = (int*)(accum + 8);                    // 256 i32
  int*   nv    = vidx + NVP;

  float* out = (float*)d_out;

  prep_kernel<<<NVP / 16, 256, 0, stream>>>(ann, n_ann, F, Fc, f2c, vidx, nv, accum);
  pgemm_kernel<<<NC / 16, 512, 0, stream>>>(P, Fc, f2c, vidx, nv, psum, accum);
  finalize_kernel<<<1, 256, 0, stream>>>(psum, vidx, nv, accum, out);
}

// Round 11
// 28.559 us; speedup vs baseline: 1.5181x; 1.5181x over previous
//
#include <hip/hip_runtime.h>
#include <hip/hip_bf16.h>

typedef float f32x4 __attribute__((ext_vector_type(4)));
typedef int   i32x4 __attribute__((ext_vector_type(4)));
typedef int   i32x8 __attribute__((ext_vector_type(8)));

#define NC 4096
#define ND 1024
#define NVP 256     // padded compact-row count (B*A = 256 annotations max)
#define EPSF 1e-10f
#define SCALE1 127  // E8M0 exponent byte for 2^0

// Fragment-tiled fp8 layout for compact F (round-8/9/10 verified):
//   frag id = kt*16 + R16, frag = 2048 B; byte = half*1024 + lane*16 + b
//   lane = hi*16+lo -> row = R16*16+lo, k = kt*128 + hi*32 + half*16 + b.

// ---------------- K1: mask+compact (redundant per block) + 1-row F convert ----------------
// 256 blocks; block b converts compact slot b (one coalesced 4 KB row read,
// no per-thread arrays -> no scratch; rule #20 fix for round-10's prep).
__global__ __launch_bounds__(256)
void fprep_kernel(const int* __restrict__ ann, int n_ann,
                  const float* __restrict__ F,
                  unsigned char* __restrict__ Fc, float* __restrict__ f2c,
                  int* __restrict__ vidx, int* __restrict__ nv,
                  float* __restrict__ accum) {
  __shared__ unsigned char mark[NC];
  __shared__ int wsum[4];
  __shared__ int vloc[NVP];
  __shared__ float rs[4];
  const int tid = threadIdx.x;
  const int lane = tid & 63, wid = tid >> 6;

  // deterministic mask + compaction, identical in every block (no global dep)
  for (int i = tid; i < NC; i += 256) mark[i] = 0;
  __syncthreads();
  for (int t = tid; t < n_ann; t += 256) {
    int idx = ann[t * 5 + 4];
    if (idx >= 0 && idx < NC) mark[idx] = 1;  // benign race: all write 1
  }
  __syncthreads();
  int base = tid * 16, lc = 0;
  #pragma unroll
  for (int k = 0; k < 16; ++k) lc += mark[base + k];
  int inc = lc;
  #pragma unroll
  for (int off = 1; off < 64; off <<= 1) {
    int v = __shfl_up(inc, off);
    if (lane >= off) inc += v;
  }
  if (lane == 63) wsum[wid] = inc;
  __syncthreads();
  int wbase = 0;
  for (int w = 0; w < wid; ++w) wbase += wsum[w];
  int pos = wbase + inc - lc;  // exclusive prefix
  for (int k = 0; k < 16; ++k)
    if (mark[base + k]) vloc[pos++] = base + k;
  const int total = wsum[0] + wsum[1] + wsum[2] + wsum[3];
  __syncthreads();  // vloc complete

  if (blockIdx.x == 0) {
    for (int i = tid; i < NVP; i += 256) vidx[i] = (i < total) ? vloc[i] : 0;
    if (tid == 0) *nv = total;
    if (tid < 8) accum[tid] = 0.f;  // re-zero every call (graph replay)
  }

  const int slot = blockIdx.x;
  if (slot >= total) return;  // padded slots: Fc frags left as-is (masked in epilogue)

  const int row = vloc[slot];
  float4 v = *reinterpret_cast<const float4*>(F + (size_t)row * ND + tid * 4);
  int pk = __builtin_amdgcn_cvt_pk_fp8_f32(v.x, v.y, 0, false);   // bytes 0,1
  pk = __builtin_amdgcn_cvt_pk_fp8_f32(v.z, v.w, pk, true);       // bytes 2,3
  {
    int d0 = tid * 4;
    int kt = d0 >> 7, hif = (d0 >> 5) & 3, half = (d0 >> 4) & 1, b = d0 & 15;
    int R16 = slot >> 4, lof = slot & 15;
    size_t fa = ((((size_t)kt * 16 + R16) * 2 + half) * 64 + hif * 16 + lof) * 16 + b;
    *reinterpret_cast<int*>(Fc + fa) = pk;
  }
  float sq = v.x * v.x + v.y * v.y + v.z * v.z + v.w * v.w;
  #pragma unroll
  for (int off = 32; off; off >>= 1) sq += __shfl_down(sq, off);
  if (lane == 0) rs[wid] = sq;
  __syncthreads();
  if (tid == 0) f2c[slot] = rs[0] + rs[1] + rs[2] + rs[3];
}

// ---------------- K2: fused P-convert + masked 256x4096 GEMM + loss ----------------
#define LDFRAG(V, BASEPTR, FID)                                               \
  do {                                                                        \
    const unsigned char* _p = (BASEPTR) + (size_t)(FID) * 2048 + lane * 16;   \
    i32x4 _l0 = *(const i32x4*)(_p);                                          \
    i32x4 _l1 = *(const i32x4*)(_p + 1024);                                   \
    V = __builtin_shufflevector(_l0, _l1, 0, 1, 2, 3, 4, 5, 6, 7);            \
  } while (0)

__global__ __launch_bounds__(512)
void pgemm_kernel(const float* __restrict__ P,
                  const unsigned char* __restrict__ Fc,
                  const float* __restrict__ f2c,
                  const int* __restrict__ vidx, const int* __restrict__ nv,
                  float* __restrict__ psum, float* __restrict__ accum) {
  // [kt][16 rows][128 B], XOR-swizzled: byte_in_row ^= (row&7)<<4
  __shared__ __attribute__((aligned(16))) unsigned char bfrag[8 * 2048];
  __shared__ float p2l[16], psl[16], redI[8], redE[8];
  const int tid = threadIdx.x;
  const int lane = tid & 63, wid = tid >> 6;
  const int bj = blockIdx.x;  // 16 P rows per block

  // Phase A: single-pass P read (coalesced), norms + fp8 swizzled LDS frags
  {
    const int r = tid >> 5;    // row 0..15
    const int seg = tid & 31;  // float4 lane within row
    const float* src = P + (size_t)(bj * 16 + r) * ND;
    float sq = 0.f, sm = 0.f;
    #pragma unroll
    for (int i = 0; i < 8; ++i) {
      float4 v = *reinterpret_cast<const float4*>(src + (seg + i * 32) * 4);
      int pk = __builtin_amdgcn_cvt_pk_fp8_f32(v.x, v.y, 0, false);
      pk = __builtin_amdgcn_cvt_pk_fp8_f32(v.z, v.w, pk, true);
      // k = (seg + i*32)*4 -> kt = i, byte-in-row = seg*4
      int addr = i * 2048 + r * 128 + ((seg * 4) ^ ((r & 7) << 4));
      *reinterpret_cast<int*>(&bfrag[addr]) = pk;
      sq += v.x * v.x + v.y * v.y + v.z * v.z + v.w * v.w;
      sm += v.x + v.y + v.z + v.w;
    }
    #pragma unroll
    for (int off = 16; off; off >>= 1) {
      sq += __shfl_down(sq, off, 32);
      sm += __shfl_down(sm, off, 32);
    }
    if ((tid & 31) == 0) {
      p2l[r] = sq; psl[r] = sm;
      psum[bj * 16 + r] = sm;   // finalize needs mask_j per row
    }
  }
  __syncthreads();

  // Phase B: 8 waves, wave w owns compact-F rows [w*32, w*32+32)
  const int lo = lane & 15, hi = lane >> 4;
  f32x4 acc0 = {0.f, 0.f, 0.f, 0.f}, acc1 = acc0;
  const int fbase = wid * 2;
  #pragma unroll 4
  for (int kt = 0; kt < 8; ++kt) {
    i32x8 a0, a1, b;
    LDFRAG(a0, Fc, kt * 16 + fbase);
    LDFRAG(a1, Fc, kt * 16 + fbase + 1);
    {
      int x = (lo & 7) << 4;
      const unsigned char* bb = &bfrag[kt * 2048 + lo * 128];
      i32x4 l0 = *reinterpret_cast<const i32x4*>(bb + ((hi * 32) ^ x));
      i32x4 l1 = *reinterpret_cast<const i32x4*>(bb + ((hi * 32 + 16) ^ x));
      b = __builtin_shufflevector(l0, l1, 0, 1, 2, 3, 4, 5, 6, 7);
    }
    acc0 = __builtin_amdgcn_mfma_scale_f32_16x16x128_f8f6f4(
        a0, b, acc0, 0, 0, 0, SCALE1, 0, SCALE1);
    acc1 = __builtin_amdgcn_mfma_scale_f32_16x16x128_f8f6f4(
        a1, b, acc1, 0, 0, 0, SCALE1, 0, SCALE1);
  }

  // Epilogue. C/D layout: col = lane&15 (P row), row = (lane>>4)*4 + reg (F row).
  int Nv = *nv;
  float intra_l = 0.f, inter_l = 0.f;
  const int gj = bj * 16 + lo;
  const float p2j = p2l[lo];
  const bool mj = psl[lo] != 0.f;
  if (mj) {
    #pragma unroll
    for (int f = 0; f < 2; ++f) {
      f32x4 a = f ? acc1 : acc0;
      #pragma unroll
      for (int r = 0; r < 4; ++r) {
        int ci = wid * 32 + f * 16 + hi * 4 + r;
        if (ci < Nv) {
          float msd = fmaxf(f2c[ci] + p2j - 2.f * a[r], 0.f) * (1.f / 1024.f);
          int gi = vidx[ci];
          if (gi == gj) {
            intra_l += msd;                 // diagonal: intra
          } else if (msd < 1.0f) {          // inter term nonzero only if sqrt(msd)<1
            float s = sqrtf(fmaxf(msd, 1e-12f));
            float e = 1.f - s;
            float e2 = e * e;
            inter_l += e2 * e2;             // (e/M)^2 * max(e,0)^2, M=1
          }
        }
      }
    }
  }
  #pragma unroll
  for (int off = 32; off; off >>= 1) {
    intra_l += __shfl_down(intra_l, off);
    inter_l += __shfl_down(inter_l, off);
  }
  if (lane == 0) { redI[wid] = intra_l; redE[wid] = inter_l; }
  __syncthreads();
  if (tid == 0) {
    float si = 0.f, se = 0.f;
    #pragma unroll
    for (int w = 0; w < 8; ++w) { si += redI[w]; se += redE[w]; }
    atomicAdd(&accum[0], si);
    atomicAdd(&accum[1], se);
  }
}

// ---------------- K3: finalize (ni = Nv; nj, nd from psum/vidx) ----------------
__global__ void finalize_kernel(const float* __restrict__ psum,
                                const int* __restrict__ vidx,
                                const int* __restrict__ nv,
                                const float* __restrict__ accum,
                                float* __restrict__ out) {
  __shared__ int r1[4], r2[4];
  int tid = threadIdx.x;
  int Nv = *nv;
  int nj = 0, nd = 0;
  for (int i = tid; i < NC; i += 256) nj += (psum[i] != 0.f);
  for (int c = tid; c < Nv; c += 256) nd += (psum[vidx[c]] != 0.f);
  #pragma unroll
  for (int off = 32; off; off >>= 1) {
    nj += __shfl_down(nj, off);
    nd += __shfl_down(nd, off);
  }
  int wid = tid >> 6, lane = tid & 63;
  if (lane == 0) { r1[wid] = nj; r2[wid] = nd; }
  __syncthreads();
  if (tid == 0) {
    float fni = (float)Nv;
    float fnj = (float)(r1[0] + r1[1] + r1[2] + r1[3]);
    float fnd = (float)(r2[0] + r2[1] + r2[2] + r2[3]);
    out[0] = accum[0] / (fnd + EPSF);
    out[1] = accum[1] / (fni * fnj - fnd + EPSF);
  }
}

extern "C" void kernel_launch(void* const* d_in, const int* in_sizes, int n_in,
                              void* d_out, int out_size, void* d_ws, size_t ws_size,
                              hipStream_t stream) {
  const float* F = (const float*)d_in[0];
  const float* P = (const float*)d_in[1];
  const int* ann = (const int*)d_in[2];
  int n_ann = in_sizes[2] / 5;

  char* ws = (char*)d_ws;
  unsigned char* Fc = (unsigned char*)ws;              // 256 KB frag-tiled fp8
  float* f2c   = (float*)(ws + (size_t)NVP * ND);      // 256 f32
  float* psum  = f2c + NVP;                            // 4096 f32
  float* accum = psum + NC;                            // 8 f32
  int*   vidx  = (int*)(accum + 8);                    // 256 i32
  int*   nv    = vidx + NVP;

  float* out = (float*)d_out;

  fprep_kernel<<<NVP, 256, 0, stream>>>(ann, n_ann, F, Fc, f2c, vidx, nv, accum);
  pgemm_kernel<<<NC / 16, 512, 0, stream>>>(P, Fc, f2c, vidx, nv, psum, accum);
  finalize_kernel<<<1, 256, 0, stream>>>(psum, vidx, nv, accum, out);
}